// Round 7
// baseline (2871.460 us; speedup 1.0000x reference)
//
#include <hip/hip_runtime.h>
#include <stdint.h>

#ifndef __has_builtin
#define __has_builtin(x) 0
#endif
#if __has_builtin(__builtin_amdgcn_fdot2)
#define HAVE_FDOT2 1
#else
#define HAVE_FDOT2 0
#endif

typedef float    f32x4 __attribute__((ext_vector_type(4)));
typedef _Float16 f16x2 __attribute__((ext_vector_type(2)));
typedef _Float16 f16x4 __attribute__((ext_vector_type(4)));
typedef _Float16 f16x8 __attribute__((ext_vector_type(8)));

#define NB 32
#define NL 2048
#define NM 256
#define NC 768            // 3 * NM packed projection columns
#define XS_SCALE 4096.0f  // int16 fixed point, range +-8, step 2.44e-4
#define XS_INV   2.44140625e-4f

__device__ __forceinline__ float dot2f(f16x2 a, f16x2 b, float c) {
#if HAVE_FDOT2
  return __builtin_amdgcn_fdot2(a, b, c, false);
#else
  float d;
  asm("v_dot2_f32_f16 %0, %1, %2, %3" : "=v"(d) : "v"(a), "v"(b), "v"(c));
  return d;
#endif
}

__device__ __forceinline__ float tanh_fast(float x) {
  x = fminf(fmaxf(x, -30.f), 30.f);
  float e = __expf(-2.f * x);
  return (1.f - e) / (1.f + e);
}
__device__ __forceinline__ float sigmoid_fast(float x) {
  x = fminf(fmaxf(x, -30.f), 30.f);
  return 1.f / (1.f + __expf(-x));
}

// ---------------- phase 1 (round-3 proven version, verbatim) ----------------
// xs[r][c] = round(4096 * sum_i u[r][i] * W(c)[c%256][i]) as int16.
// Split-f16 MFMA: u=uh+ul, W=wh+wl; acc += ul*wh + uh*wl + uh*wh.
__global__ __launch_bounds__(256) void proj_kernel(
    const float* __restrict__ u, const float* __restrict__ Wia,
    const float* __restrict__ Wic, const float* __restrict__ Wio,
    int16_t* __restrict__ xs)
{
  __shared__ _Float16 sAh[128][72];  // 72 = 64 + 8 pad, keeps 16B alignment
  __shared__ _Float16 sAl[128][72];
  __shared__ _Float16 sBh[128][72];
  __shared__ _Float16 sBl[128][72];
  const int tid = threadIdx.x;
  const int rb = blockIdx.x, cb = blockIdx.y;
  const float* W = (cb < 2) ? Wia : (cb < 4) ? Wic : Wio;
  const int wrow0 = (cb & 1) * 128;

  const int wave = tid >> 6, lane = tid & 63;
  const int wr = (wave >> 1) * 64, wc = (wave & 1) * 64;
  const int lrow = lane & 15, lk = (lane >> 4) * 8;

  f32x4 acc[4][4] = {};

  for (int kt = 0; kt < 4; ++kt) {
#pragma unroll
    for (int i = 0; i < 8; ++i) {
      int idx = tid + 256 * i;          // 0..2047 ; 16 float4 per 64-wide row
      int r = idx >> 4, c4 = idx & 15;
      f32x4 va = *reinterpret_cast<const f32x4*>(
          u + (size_t)(rb * 128 + r) * 256 + kt * 64 + c4 * 4);
      f16x4 hh, hl;
#pragma unroll
      for (int q = 0; q < 4; ++q) {
        _Float16 hi = (_Float16)va[q];
        hh[q] = hi;
        hl[q] = (_Float16)(va[q] - (float)hi);
      }
      *reinterpret_cast<f16x4*>(&sAh[r][c4 * 4]) = hh;
      *reinterpret_cast<f16x4*>(&sAl[r][c4 * 4]) = hl;
      f32x4 vb = *reinterpret_cast<const f32x4*>(
          W + (size_t)(wrow0 + r) * 256 + kt * 64 + c4 * 4);
      f16x4 gh, gl;
#pragma unroll
      for (int q = 0; q < 4; ++q) {
        _Float16 hi = (_Float16)vb[q];
        gh[q] = hi;
        gl[q] = (_Float16)(vb[q] - (float)hi);
      }
      *reinterpret_cast<f16x4*>(&sBh[r][c4 * 4]) = gh;
      *reinterpret_cast<f16x4*>(&sBl[r][c4 * 4]) = gl;
    }
    __syncthreads();
#pragma unroll
    for (int kk = 0; kk < 2; ++kk) {
      const int k0 = kk * 32 + lk;
      f16x8 afh[4], afl[4], bfh[4], bfl[4];
#pragma unroll
      for (int i = 0; i < 4; ++i) {
        afh[i] = *reinterpret_cast<const f16x8*>(&sAh[wr + i * 16 + lrow][k0]);
        afl[i] = *reinterpret_cast<const f16x8*>(&sAl[wr + i * 16 + lrow][k0]);
      }
#pragma unroll
      for (int j = 0; j < 4; ++j) {
        bfh[j] = *reinterpret_cast<const f16x8*>(&sBh[wc + j * 16 + lrow][k0]);
        bfl[j] = *reinterpret_cast<const f16x8*>(&sBl[wc + j * 16 + lrow][k0]);
      }
#pragma unroll
      for (int i = 0; i < 4; ++i)
#pragma unroll
        for (int j = 0; j < 4; ++j) {
          acc[i][j] = __builtin_amdgcn_mfma_f32_16x16x32_f16(afl[i], bfh[j], acc[i][j], 0, 0, 0);
          acc[i][j] = __builtin_amdgcn_mfma_f32_16x16x32_f16(afh[i], bfl[j], acc[i][j], 0, 0, 0);
          acc[i][j] = __builtin_amdgcn_mfma_f32_16x16x32_f16(afh[i], bfh[j], acc[i][j], 0, 0, 0);
        }
    }
    __syncthreads();
  }

  // C/D layout: col = lane&15, row = (lane>>4)*4 + q
  const size_t row0 = (size_t)rb * 128 + wr + (lane >> 4) * 4;
  const int col0 = cb * 128 + wc + (lane & 15);
#pragma unroll
  for (int i = 0; i < 4; ++i)
#pragma unroll
    for (int j = 0; j < 4; ++j)
#pragma unroll
      for (int q = 0; q < 4; ++q) {
        float v = acc[i][j][q] * XS_SCALE;
        v = fminf(fmaxf(v, -32767.f), 32767.f);
        xs[(row0 + i * 16 + q) * NC + (col0 + j * 16)] = (int16_t)__float2int_rn(v);
      }
}

// ---------------- phase 2 ----------------
// 1024 threads/wg, one wg per batch. Thread t: m = t>>2 (full 0..255),
// r = t&3, gate g = r>>1 (0: W_ha, 1: W_hc), k-half ks = r&1 (128 k-values).
// Per thread: 64 VGPRs of f16x2 weights, loaded ONCE and pinned via
// keep-alive asm (round-5 failure: compiler targeted 8 waves/EU, capped at
// 64 VGPRs, and sank the weight loads into the loop -> L2-stream-bound).
// amdgpu_waves_per_eu(4,4) pins 4 waves/EU -> 128-VGPR budget.
// Quad reduction: shfl_xor(1) sums k-halves, shfl_xor(2) exchanges gates.
// h: f16 double-buffered LDS, halves at 272B stride. One barrier per step.
__global__ __attribute__((amdgpu_flat_work_group_size(1024, 1024),
                          amdgpu_waves_per_eu(4, 4)))
void rec_kernel(
    const float* __restrict__ Wha, const float* __restrict__ Whc,
    const int16_t* __restrict__ xs, float* __restrict__ out)
{
  __shared__ __align__(16) _Float16 hbuf[2][2][136];  // 136 f16 = 272B stride
  const int t = threadIdx.x;
  const int m = t >> 2;
  const int r = t & 3;
  const int g = r >> 1;
  const int ks = r & 1;
  const int b = blockIdx.x;

  const float* Wg = g ? Whc : Wha;
  uint32_t wbits[64];
#pragma unroll
  for (int j = 0; j < 32; ++j) {
    f32x4 v = *reinterpret_cast<const f32x4*>(Wg + (size_t)m * 256 + ks * 128 + j * 4);
    f16x2 p0; p0.x = (_Float16)v.x; p0.y = (_Float16)v.y;
    f16x2 p1; p1.x = (_Float16)v.z; p1.y = (_Float16)v.w;
    wbits[2 * j]     = __builtin_bit_cast(uint32_t, p0);
    wbits[2 * j + 1] = __builtin_bit_cast(uint32_t, p1);
  }
  // Opaque-ify: compiler cannot rematerialize/sink these loads into the loop.
#pragma unroll
  for (int j = 0; j < 64; ++j) asm volatile("" : "+v"(wbits[j]));

  for (int idx = t; idx < 2 * 2 * 136; idx += 1024)
    reinterpret_cast<_Float16*>(hbuf)[idx] = (_Float16)0.f;
  __syncthreads();

  const int16_t* xrow = xs + (size_t)b * NL * NC;
  float* outb = out + (size_t)b * NL * NM;

  // prefetch pipeline, depth 2 (int16 kept raw until use)
  int pa0 = xrow[m],      pc0 = xrow[NM + m],      po0 = xrow[2 * NM + m];
  int pa1 = xrow[NC + m], pc1 = xrow[NC + NM + m], po1 = xrow[NC + 2 * NM + m];

  float h = 0.f;

#pragma unroll 2
  for (int l = 0; l < NL; ++l) {
    int na = 0, ncc = 0, no = 0;
    if (l + 2 < NL) {
      const int16_t* xr = xrow + (size_t)(l + 2) * NC;
      na = xr[m]; ncc = xr[NM + m]; no = xr[2 * NM + m];
    }

    const _Float16* hs = &hbuf[l & 1][ks][0];
    float a0 = 0.f, a1 = 0.f, a2 = 0.f, a3 = 0.f;
#pragma unroll
    for (int i = 0; i < 16; ++i) {
      f16x8 hv = *reinterpret_cast<const f16x8*>(hs + 8 * i);  // ds_read_b128
      f16x2 h0; h0.x = hv[0]; h0.y = hv[1];
      f16x2 h1; h1.x = hv[2]; h1.y = hv[3];
      f16x2 h2; h2.x = hv[4]; h2.y = hv[5];
      f16x2 h3; h3.x = hv[6]; h3.y = hv[7];
      a0 = dot2f(h0, __builtin_bit_cast(f16x2, wbits[4 * i + 0]), a0);
      a1 = dot2f(h1, __builtin_bit_cast(f16x2, wbits[4 * i + 1]), a1);
      a2 = dot2f(h2, __builtin_bit_cast(f16x2, wbits[4 * i + 2]), a2);
      a3 = dot2f(h3, __builtin_bit_cast(f16x2, wbits[4 * i + 3]), a3);
    }
    float acc = (a0 + a1) + (a2 + a3);
    acc += __shfl_xor(acc, 1);         // sum the two k-halves (same gate)
    float other = __shfl_xor(acc, 2);  // the other gate's full sum
    float sa = g ? other : acc;
    float sc = g ? acc : other;

    float xa = (float)pa0 * XS_INV;
    float xc = (float)pc0 * XS_INV;
    float xo = (float)po0 * XS_INV;
    float a = 1.f + tanh_fast(xa + sa);
    float c = sigmoid_fast(xc + sc);
    float hn = c * h + (1.f - c) * tanh_fast(xo + a * h);
    h = hn;
    if (r == 0) {
      outb[(size_t)l * NM + m] = hn;
      hbuf[(l + 1) & 1][m >> 7][m & 127] = (_Float16)hn;
    }
    pa0 = pa1; pc0 = pc1; po0 = po1;
    pa1 = na;  pc1 = ncc; po1 = no;
    __syncthreads();
  }
  if (r == 0) out[(size_t)NB * NL * NM + (size_t)b * NM + m] = h;
}

extern "C" void kernel_launch(void* const* d_in, const int* in_sizes, int n_in,
                              void* d_out, int out_size, void* d_ws, size_t ws_size,
                              hipStream_t stream) {
  (void)in_sizes; (void)n_in; (void)out_size; (void)ws_size;
  const float* u   = (const float*)d_in[0];
  const float* Wia = (const float*)d_in[1];
  const float* Wha = (const float*)d_in[2];
  const float* Wic = (const float*)d_in[3];
  const float* Whc = (const float*)d_in[4];
  const float* Wio = (const float*)d_in[5];
  float* out = (float*)d_out;
  int16_t* xs = (int16_t*)d_ws;  // [65536][768] int16 = 96 MB

  proj_kernel<<<dim3(512, 6), 256, 0, stream>>>(u, Wia, Wic, Wio, xs);
  rec_kernel<<<NB, 1024, 0, stream>>>(Wha, Whc, xs, out);
}

// Round 10
// 2842.899 us; speedup vs baseline: 1.0100x; 1.0100x over previous
//
#include <hip/hip_runtime.h>
#include <stdint.h>

#ifndef __has_builtin
#define __has_builtin(x) 0
#endif
#if __has_builtin(__builtin_amdgcn_fdot2)
#define HAVE_FDOT2 1
#else
#define HAVE_FDOT2 0
#endif

typedef float    f32x4 __attribute__((ext_vector_type(4)));
typedef _Float16 f16x2 __attribute__((ext_vector_type(2)));
typedef _Float16 f16x4 __attribute__((ext_vector_type(4)));
typedef _Float16 f16x8 __attribute__((ext_vector_type(8)));
typedef uint32_t u32x4 __attribute__((ext_vector_type(4)));

#define NB 32
#define NL 2048
#define NM 256
#define NC 768            // 3 * NM packed projection columns
#define XS_SCALE 4096.0f  // int16 fixed point, range +-8, step 2.44e-4
#define XS_INV   2.44140625e-4f
#define XS_BYTES ((size_t)65536 * 768 * 2)  // 96 MB

__device__ __forceinline__ float dot2f(f16x2 a, f16x2 b, float c) {
#if HAVE_FDOT2
  return __builtin_amdgcn_fdot2(a, b, c, false);
#else
  float d;
  asm("v_dot2_f32_f16 %0, %1, %2, %3" : "=v"(d) : "v"(a), "v"(b), "v"(c));
  return d;
#endif
}

__device__ __forceinline__ float dot2u(uint32_t hbits, uint32_t wbits, float c) {
  return dot2f(__builtin_bit_cast(f16x2, hbits), __builtin_bit_cast(f16x2, wbits), c);
}

// ds_swizzle BitMode: offset = (xor<<10)|(or<<5)|and ; and=0x1F.
// Pattern must be an ICE at the call site -> template parameter.
template <int PAT>
__device__ __forceinline__ float swz(float v) {
  int r = __builtin_amdgcn_ds_swizzle(__builtin_bit_cast(int, v), PAT);
  return __builtin_bit_cast(float, r);
}

__device__ __forceinline__ float tanh_fast(float x) {
  x = fminf(fmaxf(x, -30.f), 30.f);
  float e = __expf(-2.f * x);
  return (1.f - e) / (1.f + e);
}
__device__ __forceinline__ float sigmoid_fast(float x) {
  x = fminf(fmaxf(x, -30.f), 30.f);
  return 1.f / (1.f + __expf(-x));
}

// ---------------- phase 0: weight repack ----------------
// wf16[cidx*8 + e] holds Wg[m][ks*128 + j*8 + e] where
// cidx = w*1024 + j*64 + l ; t = w*64 + l ; m=t>>2, r=t&3, g=r>>1, ks=r&1.
// This is the exact per-(wave,lane,j) order rec_kernel loads, so every
// global_load_dwordx4 in the step loop is 64 lanes x 16B contiguous.
__global__ __launch_bounds__(256) void wconv_kernel(
    const float* __restrict__ Wha, const float* __restrict__ Whc,
    _Float16* __restrict__ wf16)
{
  int cidx = blockIdx.x * 256 + threadIdx.x;  // 0..16383
  int w = cidx >> 10, rem = cidx & 1023;
  int j = rem >> 6, l = rem & 63;
  int t = w * 64 + l;
  int m = t >> 2, r = t & 3;
  int g = r >> 1, ks = r & 1;
  const float* src = (g ? Whc : Wha) + (size_t)m * 256 + ks * 128 + j * 8;
  f16x8 o;
#pragma unroll
  for (int e = 0; e < 8; ++e) o[e] = (_Float16)src[e];
  *reinterpret_cast<f16x8*>(wf16 + (size_t)cidx * 8) = o;
}

// ---------------- phase 1 (round-3 proven version, verbatim) ----------------
__global__ __launch_bounds__(256) void proj_kernel(
    const float* __restrict__ u, const float* __restrict__ Wia,
    const float* __restrict__ Wic, const float* __restrict__ Wio,
    int16_t* __restrict__ xs)
{
  __shared__ _Float16 sAh[128][72];
  __shared__ _Float16 sAl[128][72];
  __shared__ _Float16 sBh[128][72];
  __shared__ _Float16 sBl[128][72];
  const int tid = threadIdx.x;
  const int rb = blockIdx.x, cb = blockIdx.y;
  const float* W = (cb < 2) ? Wia : (cb < 4) ? Wic : Wio;
  const int wrow0 = (cb & 1) * 128;

  const int wave = tid >> 6, lane = tid & 63;
  const int wr = (wave >> 1) * 64, wc = (wave & 1) * 64;
  const int lrow = lane & 15, lk = (lane >> 4) * 8;

  f32x4 acc[4][4] = {};

  for (int kt = 0; kt < 4; ++kt) {
#pragma unroll
    for (int i = 0; i < 8; ++i) {
      int idx = tid + 256 * i;
      int r = idx >> 4, c4 = idx & 15;
      f32x4 va = *reinterpret_cast<const f32x4*>(
          u + (size_t)(rb * 128 + r) * 256 + kt * 64 + c4 * 4);
      f16x4 hh, hl;
#pragma unroll
      for (int q = 0; q < 4; ++q) {
        _Float16 hi = (_Float16)va[q];
        hh[q] = hi;
        hl[q] = (_Float16)(va[q] - (float)hi);
      }
      *reinterpret_cast<f16x4*>(&sAh[r][c4 * 4]) = hh;
      *reinterpret_cast<f16x4*>(&sAl[r][c4 * 4]) = hl;
      f32x4 vb = *reinterpret_cast<const f32x4*>(
          W + (size_t)(wrow0 + r) * 256 + kt * 64 + c4 * 4);
      f16x4 gh, gl;
#pragma unroll
      for (int q = 0; q < 4; ++q) {
        _Float16 hi = (_Float16)vb[q];
        gh[q] = hi;
        gl[q] = (_Float16)(vb[q] - (float)hi);
      }
      *reinterpret_cast<f16x4*>(&sBh[r][c4 * 4]) = gh;
      *reinterpret_cast<f16x4*>(&sBl[r][c4 * 4]) = gl;
    }
    __syncthreads();
#pragma unroll
    for (int kk = 0; kk < 2; ++kk) {
      const int k0 = kk * 32 + lk;
      f16x8 afh[4], afl[4], bfh[4], bfl[4];
#pragma unroll
      for (int i = 0; i < 4; ++i) {
        afh[i] = *reinterpret_cast<const f16x8*>(&sAh[wr + i * 16 + lrow][k0]);
        afl[i] = *reinterpret_cast<const f16x8*>(&sAl[wr + i * 16 + lrow][k0]);
      }
#pragma unroll
      for (int j = 0; j < 4; ++j) {
        bfh[j] = *reinterpret_cast<const f16x8*>(&sBh[wc + j * 16 + lrow][k0]);
        bfl[j] = *reinterpret_cast<const f16x8*>(&sBl[wc + j * 16 + lrow][k0]);
      }
#pragma unroll
      for (int i = 0; i < 4; ++i)
#pragma unroll
        for (int j = 0; j < 4; ++j) {
          acc[i][j] = __builtin_amdgcn_mfma_f32_16x16x32_f16(afl[i], bfh[j], acc[i][j], 0, 0, 0);
          acc[i][j] = __builtin_amdgcn_mfma_f32_16x16x32_f16(afh[i], bfl[j], acc[i][j], 0, 0, 0);
          acc[i][j] = __builtin_amdgcn_mfma_f32_16x16x32_f16(afh[i], bfh[j], acc[i][j], 0, 0, 0);
        }
    }
    __syncthreads();
  }

  const size_t row0 = (size_t)rb * 128 + wr + (lane >> 4) * 4;
  const int col0 = cb * 128 + wc + (lane & 15);
#pragma unroll
  for (int i = 0; i < 4; ++i)
#pragma unroll
    for (int j = 0; j < 4; ++j)
#pragma unroll
      for (int q = 0; q < 4; ++q) {
        float v = acc[i][j][q] * XS_SCALE;
        v = fminf(fmaxf(v, -32767.f), 32767.f);
        xs[(row0 + i * 16 + q) * NC + (col0 + j * 16)] = (int16_t)__float2int_rn(v);
      }
}

// ---------------- phase 2 ----------------
// 1024 threads/wg, one wg per batch. t: m=t>>2, r=t&3, g=r>>1, ks=r&1.
// Weights are NOT register-resident (rounds 3/5/7: regalloc refuses) —
// instead streamed per step from the wconv-repacked f16 array: 16 fully
// coalesced global_load_dwordx4 per thread per step, zero address VALU
// (4 precomputed base pointers + imm offsets), zero converts. Weights are
// L2-resident (256 KB shared by all blocks). h via f16 LDS double buffer
// read as uint4 (no repack ops); quad reduction via ds_swizzle immediates.
__global__ __launch_bounds__(1024, 4) void rec_kernel(
    const _Float16* __restrict__ wf16,
    const int16_t* __restrict__ xs, float* __restrict__ out)
{
  __shared__ __align__(16) _Float16 hbuf[2][2][136];  // 272B row stride
  const int t = threadIdx.x;
  const int m = t >> 2;
  const int r = t & 3;
  const int g = r >> 1;
  const int b = blockIdx.x;

  // 4 base pointers: q covers j = 4q..4q+3 via imm offsets (jj*1024 <= 3072)
  const char* wp = (const char*)wf16 + (size_t)(t >> 6) * 16384 + (size_t)(t & 63) * 16;
  const char* wq0 = wp;
  const char* wq1 = wp + 4096;
  const char* wq2 = wp + 8192;
  const char* wq3 = wp + 12288;

  for (int idx = t; idx < 2 * 2 * 136; idx += 1024)
    reinterpret_cast<_Float16*>(hbuf)[idx] = (_Float16)0.f;
  __syncthreads();

  const int16_t* xrow = xs + (size_t)b * NL * NC;
  float* outb = out + (size_t)b * NL * NM;

  int pa0 = xrow[m],      pc0 = xrow[NM + m],      po0 = xrow[2 * NM + m];
  int pa1 = xrow[NC + m], pc1 = xrow[NC + NM + m], po1 = xrow[NC + 2 * NM + m];

  float h = 0.f;

#pragma unroll 2
  for (int l = 0; l < NL; ++l) {
    int na = 0, ncc = 0, no = 0;
    if (l + 2 < NL) {
      const int16_t* xr = xrow + (size_t)(l + 2) * NC;
      na = xr[m]; ncc = xr[NM + m]; no = xr[2 * NM + m];
    }

    const u32x4* hs = reinterpret_cast<const u32x4*>(&hbuf[l & 1][r & 1][0]);
    float a0 = 0.f, a1 = 0.f, a2 = 0.f, a3 = 0.f;
#pragma unroll
    for (int q = 0; q < 4; ++q) {
      const char* wq = (q == 0) ? wq0 : (q == 1) ? wq1 : (q == 2) ? wq2 : wq3;
#pragma unroll
      for (int jj = 0; jj < 4; ++jj) {
        const int j = q * 4 + jj;
        u32x4 wv = *reinterpret_cast<const u32x4*>(wq + jj * 1024);  // dwordx4, imm offset
        u32x4 hv = hs[j];                                            // ds_read_b128
        a0 = dot2u(hv.x, wv.x, a0);
        a1 = dot2u(hv.y, wv.y, a1);
        a2 = dot2u(hv.z, wv.z, a2);
        a3 = dot2u(hv.w, wv.w, a3);
      }
    }
    float acc = (a0 + a1) + (a2 + a3);
    acc += swz<0x041F>(acc);          // xor 1: sum the two k-halves (same gate)
    float other = swz<0x081F>(acc);   // xor 2: the other gate's full sum
    float sa = g ? other : acc;
    float sc = g ? acc : other;

    float xa = (float)pa0 * XS_INV;
    float xc = (float)pc0 * XS_INV;
    float xo = (float)po0 * XS_INV;
    float a = 1.f + tanh_fast(xa + sa);
    float c = sigmoid_fast(xc + sc);
    float hn = c * h + (1.f - c) * tanh_fast(xo + a * h);
    h = hn;
    if (r == 0) {
      outb[(size_t)l * NM + m] = hn;
      hbuf[(l + 1) & 1][m >> 7][m & 127] = (_Float16)hn;
    }
    pa0 = pa1; pc0 = pc1; po0 = po1;
    pa1 = na;  pc1 = ncc; po1 = no;
    __syncthreads();
  }
  if (r == 0) out[(size_t)NB * NL * NM + (size_t)b * NM + m] = h;
}

extern "C" void kernel_launch(void* const* d_in, const int* in_sizes, int n_in,
                              void* d_out, int out_size, void* d_ws, size_t ws_size,
                              hipStream_t stream) {
  (void)in_sizes; (void)n_in; (void)out_size; (void)ws_size;
  const float* u   = (const float*)d_in[0];
  const float* Wia = (const float*)d_in[1];
  const float* Wha = (const float*)d_in[2];
  const float* Wic = (const float*)d_in[3];
  const float* Whc = (const float*)d_in[4];
  const float* Wio = (const float*)d_in[5];
  float* out = (float*)d_out;
  int16_t* xs = (int16_t*)d_ws;                                   // 96 MB
  _Float16* wf16 = (_Float16*)((char*)d_ws + XS_BYTES);           // +256 KB

  wconv_kernel<<<64, 256, 0, stream>>>(Wha, Whc, wf16);
  proj_kernel<<<dim3(512, 6), 256, 0, stream>>>(u, Wia, Wic, Wio, xs);
  rec_kernel<<<NB, 1024, 0, stream>>>(wf16, xs, out);
}